// Round 10
// baseline (80.476 us; speedup 1.0000x reference)
//
#include <hip/hip_runtime.h>

#define NB     4
#define NPTS   8192
#define NTP    (NPTS / 2)       // 4096 target-pairs per batch
#define TPB    1024             // threads per block (16 waves)
#define QPC    16               // queries per chunk (SGPR-resident)
#define SLOTS  64               // blocks per batch; each owns 128 queries
#define NCHUNK (NPTS / SLOTS / QPC)   // 8
#define KI     (NTP / TPB)      // 4 resident target-pairs per thread

typedef float v4f __attribute__((ext_vector_type(4)));

// nq[i] = (x, y, z, 0.5||p||^2) per input1 point (queries).
// tp: per input2 target-pair p: tl=(x0,x1,y0,y1), th=(z0,z1,w0,w1).
__global__ void pack_pts(const float* __restrict__ in1, const float* __restrict__ in2,
                         v4f* __restrict__ nq, v4f* __restrict__ tp,
                         float* __restrict__ accum) {
    int i = blockIdx.x * blockDim.x + threadIdx.x;   // 49152 = 192*256 exact
    if (i == 0) accum[0] = 0.0f;                     // fold memset launch away
    if (i < NB * NPTS) {
        float x = in1[3*i], y = in1[3*i+1], z = in1[3*i+2];
        nq[i] = (v4f){x, y, z, 0.5f * (x*x + y*y + z*z)};
    } else {
        int p = i - NB * NPTS;                       // [0, NB*NTP)
        float x0 = in2[6*p+0], y0 = in2[6*p+1], z0 = in2[6*p+2];
        float x1 = in2[6*p+3], y1 = in2[6*p+4], z1 = in2[6*p+5];
        tp[2*p]   = (v4f){x0, x1, y0, y1};
        tp[2*p+1] = (v4f){z0, z1, 0.5f*(x0*x0 + y0*y0 + z0*z0),
                                  0.5f*(x1*x1 + y1*y1 + z1*z1)};
    }
}

// f(q,t) = qw + tw - q.t = 0.5||q-t||^2, computed ONCE per pair.
// Thread t holds its 8 targets (pairs t+k*TPB, k<4) RESIDENT in 32 VGPRs and
// its 8 col-mins in 8 statically-indexed registers -> the inner loop has ZERO
// vector-memory ops and ZERO LDS atomics. Queries are wave-uniform SGPRs
// (s_load 256 B per chunk). Row mins reduce per chunk (shfl + 1KB LDS);
// col partials are flushed once at kernel end as plain coalesced stores.
__launch_bounds__(TPB, 4)   // VGPR cap 128 (est ~90)
__global__ void chamfer_min(const v4f* __restrict__ nq, const v4f* __restrict__ tp,
                            unsigned* __restrict__ colbuf, float* __restrict__ accum) {
    __shared__ float red[16][QPC];

    const int slot = blockIdx.x;
    const int bb   = blockIdx.y;
    const int t    = threadIdx.x;
    const int lane = t & 63;
    const int wave = t >> 6;

    const v4f* __restrict__ Tb = tp + (size_t)bb * (2 * NTP);
    const v4f* __restrict__ Qb = nq + (size_t)bb * NPTS + slot * (NCHUNK * QPC);

    // resident targets: 8 points in 32 VGPRs, loaded once
    v4f Tl[KI], Th[KI];
#pragma unroll
    for (int k = 0; k < KI; ++k) {
        Tl[k] = Tb[2 * (t + k * TPB)];
        Th[k] = Tb[2 * (t + k * TPB) + 1];
    }

    // resident col-min accumulators (statically indexed everywhere)
    float c[2 * KI];
#pragma unroll
    for (int k = 0; k < 2 * KI; ++k) c[k] = 1e30f;

#pragma unroll 1
    for (int chunk = 0; chunk < NCHUNK; ++chunk) {
        // 16 wave-uniform queries -> SGPRs (s_load; no VGPR cost, no movs)
        float qx[QPC], qy[QPC], qz[QPC], qw[QPC];
#pragma unroll
        for (int j = 0; j < QPC; ++j) {
            v4f q = Qb[chunk * QPC + j];
            qx[j] = q.x; qy[j] = q.y; qz[j] = q.z; qw[j] = q.w;
        }

        float accR[QPC];
#pragma unroll
        for (int j = 0; j < QPC; ++j) accR[j] = 1e30f;

#pragma unroll
        for (int k = 0; k < KI; ++k) {
            float x0 = Tl[k].x, x1 = Tl[k].y, y0 = Tl[k].z, y1 = Tl[k].w;
            float z0 = Th[k].x, z1 = Th[k].y, w0 = Th[k].z, w1 = Th[k].w;
#pragma unroll
            for (int j = 0; j < QPC; j += 2) {
                float f0 = fmaf(-qx[j],   x0, fmaf(-qy[j],   y0, fmaf(-qz[j],   z0, w0 + qw[j])));
                float f1 = fmaf(-qx[j],   x1, fmaf(-qy[j],   y1, fmaf(-qz[j],   z1, w1 + qw[j])));
                float g0 = fmaf(-qx[j+1], x0, fmaf(-qy[j+1], y0, fmaf(-qz[j+1], z0, w0 + qw[j+1])));
                float g1 = fmaf(-qx[j+1], x1, fmaf(-qy[j+1], y1, fmaf(-qz[j+1], z1, w1 + qw[j+1])));
                asm("v_min3_f32 %0, %0, %1, %2" : "+v"(accR[j])   : "v"(f0), "v"(f1));
                asm("v_min3_f32 %0, %0, %1, %2" : "+v"(accR[j+1]) : "v"(g0), "v"(g1));
                asm("v_min3_f32 %0, %0, %1, %2" : "+v"(c[2*k])    : "v"(f0), "v"(g0));
                asm("v_min3_f32 %0, %0, %1, %2" : "+v"(c[2*k+1])  : "v"(f1), "v"(g1));
            }
        }

        // row epilogue: wave min -> cross-wave min (LDS) -> dist sum -> atomicAdd
#pragma unroll
        for (int j = 0; j < QPC; ++j) {
            float a = accR[j];
            a = fminf(a, __shfl_xor(a, 32));
            a = fminf(a, __shfl_xor(a, 16));
            a = fminf(a, __shfl_xor(a, 8));
            a = fminf(a, __shfl_xor(a, 4));
            a = fminf(a, __shfl_xor(a, 2));
            a = fminf(a, __shfl_xor(a, 1));
            accR[j] = a;
        }
        if (lane == 0) {
#pragma unroll
            for (int j = 0; j < QPC; j += 4)
                *(v4f*)&red[wave][j] = (v4f){accR[j], accR[j+1], accR[j+2], accR[j+3]};
        }
        __syncthreads();
        if (t < QPC) {
            float m = red[0][t];
#pragma unroll
            for (int w = 1; w < 16; ++w) m = fminf(m, red[w][t]);
            float dist = fmaxf(2.0f * m, 0.0f);
#pragma unroll
            for (int off = 8; off > 0; off >>= 1)
                dist += __shfl_xor(dist, off, 16);
            if (t == 0) atomicAdd(accum, dist);
        }
        __syncthreads();
    }

    // col partials -> global, clamped >=0 (uint bits then monotonic), coalesced
    uint2* cb = (uint2*)(colbuf + (size_t)(bb * SLOTS + slot) * NPTS);
#pragma unroll
    for (int k = 0; k < KI; ++k) {
        uint2 v;
        v.x = __float_as_uint(fmaxf(c[2*k],   0.0f));
        v.y = __float_as_uint(fmaxf(c[2*k+1], 0.0f));
        cb[t + k * TPB] = v;
    }
}

// Reduce SLOTS slot-partials per target, sum distances, atomicAdd.
__global__ void col_combine(const unsigned* __restrict__ colbuf, float* __restrict__ accum) {
    int tid = blockIdx.x * blockDim.x + threadIdx.x;   // 32768 threads
    int bb  = tid >> 13;
    int m   = tid & (NPTS - 1);
    const unsigned* cb = colbuf + (size_t)bb * SLOTS * NPTS + m;
    unsigned k = ~0u;
#pragma unroll 8
    for (int s = 0; s < SLOTS; ++s) k = min(k, cb[(size_t)s * NPTS]);
    float dist = 2.0f * __uint_as_float(k);            // already clamped >= 0
    for (int off = 32; off > 0; off >>= 1) dist += __shfl_xor(dist, off, 64);
    if ((threadIdx.x & 63) == 0) atomicAdd(accum, dist);
}

__global__ void finish(const float* __restrict__ accum, float* __restrict__ out) {
    out[0] = accum[0] * (1.0f / (NB * NPTS));
}

extern "C" void kernel_launch(void* const* d_in, const int* in_sizes, int n_in,
                              void* d_out, int out_size, void* d_ws, size_t ws_size,
                              hipStream_t stream) {
    const float* in1 = (const float*)d_in[0];
    const float* in2 = (const float*)d_in[1];

    char* ws = (char*)d_ws;
    float*    accum  = (float*)ws;                               // 1 float
    v4f*      nq     = (v4f*)(ws + 256);                         // 512 KB
    v4f*      tp     = nq + (size_t)NB * NPTS;                   // 512 KB
    unsigned* colbuf = (unsigned*)(tp + (size_t)NB * NTP * 2);   // 8.4 MB

    pack_pts<<<dim3((NB * NPTS + NB * NTP) / 256), 256, 0, stream>>>(in1, in2, nq, tp, accum);

    chamfer_min<<<dim3(SLOTS, NB), TPB, 0, stream>>>(nq, tp, colbuf, accum);

    col_combine<<<dim3(128), 256, 0, stream>>>(colbuf, accum);

    finish<<<1, 1, 0, stream>>>(accum, (float*)d_out);
}

// Round 11
// 75.725 us; speedup vs baseline: 1.0627x; 1.0627x over previous
//
#include <hip/hip_runtime.h>

#define NB     4
#define NPTS   8192
#define NTP    (NPTS / 2)       // 4096 target-pairs per batch
#define TPB    512              // threads per block (8 waves)
#define WPB2   (TPB / 64)       // 8
#define QPC    16               // queries per chunk (SGPR-resident)
#define SLOTS  128              // blocks per batch; each owns 64 queries
#define NCHUNK (NPTS / SLOTS / QPC)   // 4
#define KI     (NTP / TPB)      // 8 resident target-pairs per thread
#define QPB3   (NCHUNK * QPC)   // 64 queries per block

typedef float v4f __attribute__((ext_vector_type(4)));

// nq[i] = (x, y, z, 0.5||p||^2) per input1 point (queries).
// tp: per input2 target-pair p: tl=(x0,x1,y0,y1), th=(z0,z1,w0,w1).
__global__ void pack_pts(const float* __restrict__ in1, const float* __restrict__ in2,
                         v4f* __restrict__ nq, v4f* __restrict__ tp,
                         float* __restrict__ accum) {
    int i = blockIdx.x * blockDim.x + threadIdx.x;   // 49152 = 192*256 exact
    if (i == 0) accum[0] = 0.0f;
    if (i < NB * NPTS) {
        float x = in1[3*i], y = in1[3*i+1], z = in1[3*i+2];
        nq[i] = (v4f){x, y, z, 0.5f * (x*x + y*y + z*z)};
    } else {
        int p = i - NB * NPTS;                       // [0, NB*NTP)
        float x0 = in2[6*p+0], y0 = in2[6*p+1], z0 = in2[6*p+2];
        float x1 = in2[6*p+3], y1 = in2[6*p+4], z1 = in2[6*p+5];
        tp[2*p]   = (v4f){x0, x1, y0, y1};
        tp[2*p+1] = (v4f){z0, z1, 0.5f*(x0*x0 + y0*y0 + z0*z0),
                                  0.5f*(x1*x1 + y1*y1 + z1*z1)};
    }
}

// f(q,t) = qw + tw - q.t = 0.5||q-t||^2, computed ONCE per pair.
// Thread t holds its 16 targets PINNED in 64 VGPRs (R10: without the pin the
// compiler demoted them to per-chunk reloads; VGPR=48 proved it) and 16
// col-mins in registers. NO BARRIERS in the main loop: per-wave row partials
// go to private LDS slots (plain ds_write by lane 0), so waves drift out of
// phase and hide each other's per-chunk s_load (query) stalls — R10's
// per-chunk __syncthreads convoy made all 16 waves stall together.
__launch_bounds__(TPB, 4)   // VGPR cap 128 (est ~116 with pins)
__global__ void chamfer_min(const v4f* __restrict__ nq, const v4f* __restrict__ tp,
                            unsigned* __restrict__ colbuf, float* __restrict__ accum) {
    __shared__ float rowWaveMin[WPB2][QPB3];   // [8][64] = 2 KB

    const int slot = blockIdx.x;
    const int bb   = blockIdx.y;
    const int t    = threadIdx.x;
    const int lane = t & 63;
    const int wave = t >> 6;

    const v4f* __restrict__ Tb = tp + (size_t)bb * (2 * NTP);
    const v4f* __restrict__ Qb = nq + (size_t)bb * NPTS + slot * QPB3;

    // resident targets: 16 points in 64 VGPRs, loaded once and PINNED
    v4f Tl[KI], Th[KI];
#pragma unroll
    for (int k = 0; k < KI; ++k) {
        Tl[k] = Tb[2 * (t + k * TPB)];
        Th[k] = Tb[2 * (t + k * TPB) + 1];
    }
#pragma unroll
    for (int k = 0; k < KI; ++k) asm("" : "+v"(Tl[k]), "+v"(Th[k]));

    float c[2 * KI];
#pragma unroll
    for (int k = 0; k < 2 * KI; ++k) c[k] = 1e30f;

#pragma unroll 1
    for (int chunk = 0; chunk < NCHUNK; ++chunk) {
        // 16 wave-uniform queries -> SGPRs (s_load; free operand in FMAs)
        float qx[QPC], qy[QPC], qz[QPC], qw[QPC];
#pragma unroll
        for (int j = 0; j < QPC; ++j) {
            v4f q = Qb[chunk * QPC + j];
            qx[j] = q.x; qy[j] = q.y; qz[j] = q.z; qw[j] = q.w;
        }

        float accR[QPC];
#pragma unroll
        for (int j = 0; j < QPC; ++j) accR[j] = 1e30f;

#pragma unroll
        for (int k = 0; k < KI; ++k) {
            float x0 = Tl[k].x, x1 = Tl[k].y, y0 = Tl[k].z, y1 = Tl[k].w;
            float z0 = Th[k].x, z1 = Th[k].y, w0 = Th[k].z, w1 = Th[k].w;
#pragma unroll
            for (int j = 0; j < QPC; j += 2) {
                float f0 = fmaf(-qx[j],   x0, fmaf(-qy[j],   y0, fmaf(-qz[j],   z0, w0 + qw[j])));
                float f1 = fmaf(-qx[j],   x1, fmaf(-qy[j],   y1, fmaf(-qz[j],   z1, w1 + qw[j])));
                float g0 = fmaf(-qx[j+1], x0, fmaf(-qy[j+1], y0, fmaf(-qz[j+1], z0, w0 + qw[j+1])));
                float g1 = fmaf(-qx[j+1], x1, fmaf(-qy[j+1], y1, fmaf(-qz[j+1], z1, w1 + qw[j+1])));
                asm("v_min3_f32 %0, %0, %1, %2" : "+v"(accR[j])   : "v"(f0), "v"(f1));
                asm("v_min3_f32 %0, %0, %1, %2" : "+v"(accR[j+1]) : "v"(g0), "v"(g1));
                asm("v_min3_f32 %0, %0, %1, %2" : "+v"(c[2*k])    : "v"(f0), "v"(g0));
                asm("v_min3_f32 %0, %0, %1, %2" : "+v"(c[2*k+1])  : "v"(f1), "v"(g1));
            }
        }

        // per-wave row partials -> private LDS slot; NO barrier, NO atomics
#pragma unroll
        for (int j = 0; j < QPC; ++j) {
            float a = accR[j];
            a = fminf(a, __shfl_xor(a, 32));
            a = fminf(a, __shfl_xor(a, 16));
            a = fminf(a, __shfl_xor(a, 8));
            a = fminf(a, __shfl_xor(a, 4));
            a = fminf(a, __shfl_xor(a, 2));
            a = fminf(a, __shfl_xor(a, 1));
            if (lane == 0) rowWaveMin[wave][chunk * QPC + j] = a;
        }
    }

    __syncthreads();   // the ONLY block barrier

    // fold 8 wave-partials per query; one wave sums the 64 query dists
    if (t < QPB3) {
        float m = rowWaveMin[0][t];
#pragma unroll
        for (int w = 1; w < WPB2; ++w) m = fminf(m, rowWaveMin[w][t]);
        float dist = fmaxf(2.0f * m, 0.0f);
#pragma unroll
        for (int off = 32; off > 0; off >>= 1)
            dist += __shfl_xor(dist, off, 64);
        if (t == 0) atomicAdd(accum, dist);
    }

    // col partials -> global, clamped >=0 (float bits become monotonic key)
    uint2* cb = (uint2*)(colbuf + (size_t)(bb * SLOTS + slot) * NPTS);
#pragma unroll
    for (int k = 0; k < KI; ++k) {
        uint2 v;
        v.x = __float_as_uint(fmaxf(c[2*k],   0.0f));
        v.y = __float_as_uint(fmaxf(c[2*k+1], 0.0f));
        cb[t + k * TPB] = v;
    }
}

// Reduce SLOTS slot-partials per target, sum distances, atomicAdd.
__global__ void col_combine(const unsigned* __restrict__ colbuf, float* __restrict__ accum) {
    int tid = blockIdx.x * blockDim.x + threadIdx.x;   // 32768 threads
    int bb  = tid >> 13;
    int m   = tid & (NPTS - 1);
    const unsigned* cb = colbuf + (size_t)bb * SLOTS * NPTS + m;
    unsigned k = ~0u;
#pragma unroll 8
    for (int s = 0; s < SLOTS; ++s) k = min(k, cb[(size_t)s * NPTS]);
    float dist = 2.0f * __uint_as_float(k);            // already clamped >= 0
    for (int off = 32; off > 0; off >>= 1) dist += __shfl_xor(dist, off, 64);
    if ((threadIdx.x & 63) == 0) atomicAdd(accum, dist);
}

__global__ void finish(const float* __restrict__ accum, float* __restrict__ out) {
    out[0] = accum[0] * (1.0f / (NB * NPTS));
}

extern "C" void kernel_launch(void* const* d_in, const int* in_sizes, int n_in,
                              void* d_out, int out_size, void* d_ws, size_t ws_size,
                              hipStream_t stream) {
    const float* in1 = (const float*)d_in[0];
    const float* in2 = (const float*)d_in[1];

    char* ws = (char*)d_ws;
    float*    accum  = (float*)ws;                               // 1 float
    v4f*      nq     = (v4f*)(ws + 256);                         // 512 KB
    v4f*      tp     = nq + (size_t)NB * NPTS;                   // 512 KB
    unsigned* colbuf = (unsigned*)(tp + (size_t)NB * NTP * 2);   // 16.8 MB (ws >= 34 MB per R9)

    pack_pts<<<dim3((NB * NPTS + NB * NTP) / 256), 256, 0, stream>>>(in1, in2, nq, tp, accum);

    chamfer_min<<<dim3(SLOTS, NB), TPB, 0, stream>>>(nq, tp, colbuf, accum);

    col_combine<<<dim3(128), 256, 0, stream>>>(colbuf, accum);

    finish<<<1, 1, 0, stream>>>(accum, (float*)d_out);
}